// Round 20
// baseline (51.817 us; speedup 1.0000x reference)
//
#include <hip/hip_runtime.h>
#include <math.h>

#define NN 8
#define CC 256        // channels per tensor (concat input has 2*CC = 512)
#define HH 48
#define WW 48
#define HW 2304       // 48*48
#define OCONV 18      // offset-conv output channels (2*K)
#define KTAP 9        // deform taps
#define G1 16         // split-K groups for offset conv (512/16 = 32 ch/group)
#define NSZ (NN * OCONV * HW)   // 331776
#define MM 96         // padded deform-GEMM rows (81 used)
#define NCG 64        // 512 ch / 8
#define PPL 2704      // padded plane sites: 52*52 (2-site zero border)

#define NCONVB 1536   // conv blocks in merged kernel
#define NGEMMB 576    // gemm blocks in merged kernel (3 waves each)

typedef __attribute__((ext_vector_type(8))) short short8;   // 8 bf16 (4 VGPRs)
typedef __attribute__((ext_vector_type(16))) float f32x16;  // 32x32 MFMA acc

static __device__ __forceinline__ unsigned short f2bf(float f) {
  unsigned u = __float_as_uint(f);
  unsigned r = (u + 0x7fffu + ((u >> 16) & 1u)) >> 16;   // round-to-nearest-even
  return (unsigned short)r;
}

// ---------------------------------------------------------------------------
// Kernel 1 (merged): blocks 0..9215 transpose query+support ->
// qsT[n][cg][52x52 padded][8ch] bf16 (2-site zero border, XCD-pinned);
// blocks 9216..10911 do weight prep (Wm conv A-frags, wkm deform A-frags).
// ---------------------------------------------------------------------------
__global__ __launch_bounds__(256) void transpose_prep_kernel(
    const float* __restrict__ support, const float* __restrict__ query,
    const float* __restrict__ w_off, const float* __restrict__ w_kernel,
    unsigned short* __restrict__ qsT, unsigned short* __restrict__ Wm,
    unsigned short* __restrict__ wkm) {
  const int bid = blockIdx.x;
  const int tid = threadIdx.x;

  if (bid >= 9216) {                  // ---- weight prep part ----
    const int b = bid - 9216;
    if (b < 1600) {
      const int i = b * 256 + tid;    // < 409600
      const int j  = i & 7;
      const int o  = (i >> 3) & 31;
      const int cb = (i >> 8) & 63;
      const int t  = i >> 14;
      float v = 0.f;
      if (o < OCONV) v = w_off[(size_t)(o * (2 * CC) + cb * 8 + j) * 25 + t];
      Wm[i] = f2bf(v);
    } else {
      const int i = (b - 1600) * 256 + tid;
      if (i < 3 * 16 * 2 * 32 * 8) {
        const int j    = i & 7;
        const int r    = (i >> 3) & 31;
        const int half = (i >> 8) & 1;
        const int cb   = (i >> 9) & 15;
        const int mt   = i >> 13;
        const int m = mt * 32 + r;
        const int c = cb * 16 + half * 8 + j;
        float v = 0.f;
        if (m < 81) {
          const int k = m / 9, o = m % 9;
          v = w_kernel[(size_t)(o * CC + c) * KTAP + k];
        }
        wkm[i] = f2bf(v);
      }
    }
    return;
  }

  // ---- transpose part (bid 0..9215 = 8n * 72pt * 16ct) ----
  const int n    = bid & 7;           // XCD pin
  const int rest = bid >> 3;
  const int pt = rest % 72;
  const int ct = rest / 72;           // 0..15; 32-ch block
  const int p0 = pt * 32;

  __shared__ float tile[32][33];

  const float* plane = ((ct < 8) ? query : support) +
                       ((size_t)n * CC + (ct & 7) * 32) * HW;
#pragma unroll
  for (int j = 0; j < 4; ++j) {
    const int idx = tid + j * 256;
    const int cc = idx >> 5, pp = idx & 31;
    tile[pp][cc] = plane[(size_t)cc * HW + p0 + pp];
  }
  __syncthreads();

  unsigned short* qn = qsT + (size_t)n * NCG * PPL * 8;
  const int cgbase = ((ct < 8) ? 0 : 32) + (ct & 7) * 4;

  if (tid < 128) {
    const int pp  = tid & 31;
    const int cgl = tid >> 5;          // 0..3
    const int s = p0 + pp;
    const int y = s / 48, x = s % 48;
    const int psite = (y + 2) * 52 + (x + 2);
    const float* row = &tile[pp][cgl * 8];
    uint4 w;
    w.x = (unsigned)f2bf(row[0]) | ((unsigned)f2bf(row[1]) << 16);
    w.y = (unsigned)f2bf(row[2]) | ((unsigned)f2bf(row[3]) << 16);
    w.z = (unsigned)f2bf(row[4]) | ((unsigned)f2bf(row[5]) << 16);
    w.w = (unsigned)f2bf(row[6]) | ((unsigned)f2bf(row[7]) << 16);
    *(uint4*)(qn + ((size_t)(cgbase + cgl) * PPL + psite) * 8) = w;
  }

  // zero border: 400 border sites x 4 cg planes, done by pt==0 blocks
  if (pt == 0) {
    const uint4 zz = make_uint4(0u, 0u, 0u, 0u);
    for (int z = tid; z < 1600; z += 256) {
      const int cgl = z / 400;
      const int e   = z % 400;
      int row, col;
      if (e < 104)      { row = e / 52;              col = e % 52; }          // rows 0,1
      else if (e < 208) { row = 50 + (e - 104) / 52; col = (e - 104) % 52; }  // rows 50,51
      else {
        const int f = e - 208;                                               // cols 0,1,50,51
        row = 2 + f / 4;
        const int cs = f % 4;
        col = (cs < 2) ? cs : (48 + cs);
      }
      *(uint4*)(qn + ((size_t)(cgbase + cgl) * PPL + row * 52 + col) * 8) = zz;
    }
  }
}

// ---------------------------------------------------------------------------
// Kernel 2 (merged): blocks 0..1535 = offset conv (G1=16, 26.6KB LDS,
// asymmetric-depth pipeline, XCD-pinned); blocks 1536..2111 = deform GEMM
// D[n][m][site]. s_setprio(1) wraps MFMA clusters (T5): per-tap phase split
// gives waves role diversity, so priority arbitration keeps the matrix pipe
// fed. 192 threads/block.
// ---------------------------------------------------------------------------
__global__ __launch_bounds__(192, 2) void conv_gemm_kernel(
    const unsigned short* __restrict__ qsT,
    const unsigned short* __restrict__ Wm,
    const unsigned short* __restrict__ wkm,
    float* __restrict__ offs_part, float* __restrict__ D) {
  const int bid = blockIdx.x;
  const int tid = threadIdx.x;
  const int w = tid >> 6;
  const int l = tid & 63;
  const int l31 = l & 31;
  const int half = l >> 5;

  __shared__ __align__(16) unsigned short lds[1664 * 8];   // 26,624 B (conv only)

  if (bid >= NCONVB) {
    // ---- deform GEMM part: D[n][m][site] = sum_c wk * sup, m=k*9+o ----
    const int b2 = bid - NCONVB;        // 0..575
    const int n    = b2 & 7;            // XCD pin
    const int rest = b2 >> 3;           // 0..71
    const int wid = rest * 3 + w;       // 0..215
    const int st = wid % 72;            // site tile
    const int mt = wid / 72;            // m tile 0..2
    const int s = st * 32 + l31;
    const int psite = (s / 48) * 52 + (s % 48) + 2 * 52 + 2;

    const unsigned short* qn = qsT + (size_t)n * NCG * PPL * 8;
    const unsigned short* asrc = wkm + (size_t)(half * 32 + l31) * 8;

    f32x16 acc = {0.f, 0.f, 0.f, 0.f, 0.f, 0.f, 0.f, 0.f,
                  0.f, 0.f, 0.f, 0.f, 0.f, 0.f, 0.f, 0.f};

    __builtin_amdgcn_s_setprio(1);
#pragma unroll
    for (int cb = 0; cb < 16; ++cb) {
      const int cg = 32 + cb * 2 + half;
      const short8 b = *(const short8*)(qn + ((size_t)cg * PPL + psite) * 8);
      const short8 a = *(const short8*)(asrc + (size_t)((mt * 16 + cb) * 2) * 256);
      acc = __builtin_amdgcn_mfma_f32_32x32x16_bf16(a, b, acc, 0, 0, 0);
    }
    __builtin_amdgcn_s_setprio(0);

    float* Dn = D + (size_t)n * MM * HW;
#pragma unroll
    for (int r = 0; r < 16; ++r) {
      const int m = mt * 32 + (r & 3) + 8 * (r >> 2) + 4 * half;
      Dn[(size_t)m * HW + s] = acc[r];
    }
    return;
  }

  // ---- offset conv part (bid 0..1535 = 12rt * 16g * 8n) ----
  const int n  = bid & 7;            // XCD pin
  const int r2 = bid >> 3;           // 0..191
  const int g  = r2 & 15;            // channel group (32 ch)
  const int rt = r2 >> 4;            // 0..11 (4 image rows each)

  // ---- stage: cg 0..3 (abs g*4+cg), padded rows rt*4..rt*4+7, cols 0..51 ----
  const unsigned short* qn = qsT + ((size_t)n * NCG + g * 4) * PPL * 8;
  for (int c = tid; c < 1664; c += 192) {
    const int cg  = c / 416;
    const int rem = c - cg * 416;                    // rr*52 + col
    const uint4 v = *(const uint4*)(qn + ((size_t)cg * PPL + rt * 4 * 52 + rem) * 8);
    *(uint4*)(lds + (size_t)c * 8) = v;
  }
  __syncthreads();

  const int si0 = w * 64 + l31;      // first site (0..191 within row tile)
  const int si1 = si0 + 32;          // second site
  const int rrA = si0 / 48, xA = si0 % 48;
  const int rrB = si1 / 48, xB = si1 % 48;

  const unsigned short* lbase0 = lds + (half * 416 + rrA * 52 + xA) * 8;
  const unsigned short* lbase1 = lds + (half * 416 + rrB * 52 + xB) * 8;
  const unsigned short* abase = Wm + (size_t)((g * 4 + half) * 32 + l31) * 8;
  // A(t,kk) = abase + t*16384 + kk*512 (shorts); cb = g*4 + kk*2 + half
  // B(t,kk,site) = lbase + kk*6656 + ((t/5)*52 + t%5)*8 (shorts, compile-time)

  f32x16 acc0 = {0.f, 0.f, 0.f, 0.f, 0.f, 0.f, 0.f, 0.f,
                 0.f, 0.f, 0.f, 0.f, 0.f, 0.f, 0.f, 0.f};
  f32x16 acc1 = acc0;

  short8 a[3][2];                    // [t%3][kk] — A prefetched 2 taps ahead
  short8 b0[2][2], b1[2][2];         // [t&1][kk] — B prefetched 1 tap ahead

  // prologue: A taps 0,1; B tap 0
#pragma unroll
  for (int kk = 0; kk < 2; ++kk) {
    a[0][kk]  = *(const short8*)(abase + 0 * 16384 + kk * 512);
    a[1][kk]  = *(const short8*)(abase + 1 * 16384 + kk * 512);
    b0[0][kk] = *(const short8*)(lbase0 + kk * 6656);
    b1[0][kk] = *(const short8*)(lbase1 + kk * 6656);
  }

#pragma unroll
  for (int t = 0; t < 25; ++t) {
    const int bc = t & 1;            // current B buffer
    const int ac = t % 3;            // current A buffer
    if (t < 24) {
      const int tn = t + 1;
      const int loff = ((tn / 5) * 52 + (tn % 5)) * 8;   // compile-time
#pragma unroll
      for (int kk = 0; kk < 2; ++kk) {
        b0[bc ^ 1][kk] = *(const short8*)(lbase0 + kk * 6656 + loff);
        b1[bc ^ 1][kk] = *(const short8*)(lbase1 + kk * 6656 + loff);
      }
    }
    if (t < 23) {
      const int ta = t + 2;
#pragma unroll
      for (int kk = 0; kk < 2; ++kk)
        a[(t + 2) % 3][kk] = *(const short8*)(abase + ta * 16384 + kk * 512);
    }
    __builtin_amdgcn_sched_barrier(0);
    __builtin_amdgcn_s_setprio(1);
#pragma unroll
    for (int kk = 0; kk < 2; ++kk) {
      acc0 = __builtin_amdgcn_mfma_f32_32x32x16_bf16(a[ac][kk], b0[bc][kk], acc0, 0, 0, 0);
      acc1 = __builtin_amdgcn_mfma_f32_32x32x16_bf16(a[ac][kk], b1[bc][kk], acc1, 0, 0, 0);
    }
    __builtin_amdgcn_s_setprio(0);
  }

  float* dst = offs_part + ((size_t)(g * NN + n) * OCONV) * HW;
  const int s0 = rt * 192 + si0;
  const int s1 = rt * 192 + si1;
#pragma unroll
  for (int r = 0; r < 16; ++r) {
    const int o = (r & 3) + 8 * (r >> 2) + 4 * half;
    if (o < OCONV) {
      dst[(size_t)o * HW + s0] = acc0[r];
      dst[(size_t)o * HW + s1] = acc1[r];
    }
  }
}

// ---------------------------------------------------------------------------
// Kernel 3: fold split-K partials + precompute bilinear params.
// par[n][k][p][8]: {w00,w01,w10,w11 (f32), a00,a01,a10,a11 (int)}. XCD-pinned.
// ---------------------------------------------------------------------------
__global__ __launch_bounds__(256) void param_kernel(
    const float* __restrict__ offs_part, float* __restrict__ par) {
  const int n  = blockIdx.x & 7;       // XCD pin
  const int j  = blockIdx.x >> 3;      // 0..80
  const int il = j * 256 + threadIdx.x;
  const int p = il % HW;
  const int k = il / HW;
  const int y = p / WW, x = p % WW;

  float dy = 0.f, dx = 0.f;
#pragma unroll
  for (int g = 0; g < G1; ++g) {
    const float* base = offs_part + ((size_t)(g * NN + n) * OCONV + 2 * k) * HW + p;
    dy += base[0];
    dx += base[HW];
  }
  const float sy = (float)(y + k / 3 - 1) + dy;
  const float sx = (float)(x + k % 3 - 1) + dx;
  const float y0 = floorf(sy), x0 = floorf(sx);
  const float ly = sy - y0,  lx = sx - x0;
  const float y1 = y0 + 1.f, x1 = x0 + 1.f;
  const float vy0 = (y0 >= 0.f && y0 <= (float)(HH - 1)) ? 1.f : 0.f;
  const float vy1 = (y1 >= 0.f && y1 <= (float)(HH - 1)) ? 1.f : 0.f;
  const float vx0 = (x0 >= 0.f && x0 <= (float)(WW - 1)) ? 1.f : 0.f;
  const float vx1 = (x1 >= 0.f && x1 <= (float)(WW - 1)) ? 1.f : 0.f;
  const int yi0 = min(max((int)y0, 0), HH - 1);
  const int yi1 = min(max((int)y1, 0), HH - 1);
  const int xi0 = min(max((int)x0, 0), WW - 1);
  const int xi1 = min(max((int)x1, 0), WW - 1);

  float* d = par + ((size_t)n * KTAP * HW + il) * 8;
  d[0] = (1.f - ly) * (1.f - lx) * vy0 * vx0;
  d[1] = (1.f - ly) * lx * vy0 * vx1;
  d[2] = ly * (1.f - lx) * vy1 * vx0;
  d[3] = ly * lx * vy1 * vx1;
  int* di = (int*)d;
  di[4] = yi0 * WW + xi0;
  di[5] = yi0 * WW + xi1;
  di[6] = yi1 * WW + xi0;
  di[7] = yi1 * WW + xi1;
}

// ---------------------------------------------------------------------------
// Kernel 4: combine + sigmoid. One thread per output element. XCD-pinned.
// ---------------------------------------------------------------------------
__global__ __launch_bounds__(256) void deform_combine(
    const float* __restrict__ D, const float* __restrict__ par,
    float* __restrict__ out) {
  const int bid = blockIdx.x;          // 648 = 81 * 8n
  const int n  = bid & 7;              // XCD pin
  const int rr = bid >> 3;             // 0..80
  const int o  = rr / 9;
  const int p  = (rr % 9) * 256 + threadIdx.x;

  const float* Dn = D + (size_t)n * MM * HW;
  const float* pb = par + ((size_t)n * KTAP * HW + p) * 8;

  float s = 0.f;
#pragma unroll
  for (int k = 0; k < KTAP; ++k) {
    const float4 wv = *(const float4*)(pb + (size_t)k * HW * 8);
    const int4  av = *(const int4*)(pb + (size_t)k * HW * 8 + 4);
    const float* base = Dn + (size_t)(k * 9 + o) * HW;
    s += wv.x * base[av.x] + wv.y * base[av.y] +
         wv.z * base[av.z] + wv.w * base[av.w];
  }
  out[((size_t)n * KTAP + o) * HW + p] = 1.f / (1.f + __expf(-s));
}

extern "C" void kernel_launch(void* const* d_in, const int* in_sizes, int n_in,
                              void* d_out, int out_size, void* d_ws, size_t ws_size,
                              hipStream_t stream) {
  const float* support  = (const float*)d_in[0];
  const float* query    = (const float*)d_in[1];
  const float* w_off    = (const float*)d_in[2];
  const float* w_kernel = (const float*)d_in[3];
  float* out = (float*)d_out;

  // ws layout (float units), ~46 MB (no aliasing; ws is ~268 MB):
  // [qsT 22.2MB][par 5.3MB][Wm 0.82MB][wkm 0.1MB][offs_part 21.2MB][D 7.1MB]
  float* base = (float*)d_ws;
  unsigned short* qsT = (unsigned short*)base;                  // 8*64*PPL*8 bf16
  float* par = base + (size_t)NN * NCG * PPL * 8 / 2;           // NN*9*HW*8 f
  float* tail = par + (size_t)NN * KTAP * HW * 8;
  unsigned short* Wm  = (unsigned short*)tail;                  // 409600 bf16 = 204800 f
  unsigned short* wkm = (unsigned short*)(tail + 204800);       // 49152 bf16 = 24576 f
  float* offs_part = tail + 204800 + 24576;                     // G1*NSZ f
  float* D = offs_part + (size_t)G1 * NSZ;                      // NN*MM*HW f

  transpose_prep_kernel<<<9216 + 1696, 256, 0, stream>>>(
      support, query, w_off, w_kernel, qsT, Wm, wkm);
  conv_gemm_kernel<<<NCONVB + NGEMMB, 192, 0, stream>>>(qsT, Wm, wkm, offs_part, D);
  param_kernel<<<81 * 8, 256, 0, stream>>>(offs_part, par);
  deform_combine<<<81 * 8, 256, 0, stream>>>(D, par, out);
}

// Round 21
// 49.468 us; speedup vs baseline: 1.0475x; 1.0475x over previous
//
#include <hip/hip_runtime.h>
#include <math.h>

#define NN 8
#define CC 256        // channels per tensor (concat input has 2*CC = 512)
#define HH 48
#define WW 48
#define HW 2304       // 48*48
#define OCONV 18      // offset-conv output channels (2*K)
#define KTAP 9        // deform taps
#define G1 16         // split-K groups for offset conv (512/16 = 32 ch/group)
#define NSZ (NN * OCONV * HW)   // 331776
#define MM 96         // padded deform-GEMM rows (81 used)
#define NCG 64        // 512 ch / 8
#define PPL 2704      // padded plane sites: 52*52 (2-site zero border)

#define NCONVB 1536   // conv blocks in merged kernel
#define NGEMMB 576    // gemm blocks in merged kernel (3 waves each)

typedef __attribute__((ext_vector_type(8))) short short8;   // 8 bf16 (4 VGPRs)
typedef __attribute__((ext_vector_type(16))) float f32x16;  // 32x32 MFMA acc

static __device__ __forceinline__ unsigned short f2bf(float f) {
  unsigned u = __float_as_uint(f);
  unsigned r = (u + 0x7fffu + ((u >> 16) & 1u)) >> 16;   // round-to-nearest-even
  return (unsigned short)r;
}

// ---------------------------------------------------------------------------
// Kernel 1 (merged): blocks 0..9215 transpose query+support ->
// qsT[n][cg][52x52 padded][8ch] bf16 (2-site zero border, XCD-pinned);
// blocks 9216..10911 do weight prep (Wm conv A-frags, wkm deform A-frags).
// ---------------------------------------------------------------------------
__global__ __launch_bounds__(256) void transpose_prep_kernel(
    const float* __restrict__ support, const float* __restrict__ query,
    const float* __restrict__ w_off, const float* __restrict__ w_kernel,
    unsigned short* __restrict__ qsT, unsigned short* __restrict__ Wm,
    unsigned short* __restrict__ wkm) {
  const int bid = blockIdx.x;
  const int tid = threadIdx.x;

  if (bid >= 9216) {                  // ---- weight prep part ----
    const int b = bid - 9216;
    if (b < 1600) {
      const int i = b * 256 + tid;    // < 409600
      const int j  = i & 7;
      const int o  = (i >> 3) & 31;
      const int cb = (i >> 8) & 63;
      const int t  = i >> 14;
      float v = 0.f;
      if (o < OCONV) v = w_off[(size_t)(o * (2 * CC) + cb * 8 + j) * 25 + t];
      Wm[i] = f2bf(v);
    } else {
      const int i = (b - 1600) * 256 + tid;
      if (i < 3 * 16 * 2 * 32 * 8) {
        const int j    = i & 7;
        const int r    = (i >> 3) & 31;
        const int half = (i >> 8) & 1;
        const int cb   = (i >> 9) & 15;
        const int mt   = i >> 13;
        const int m = mt * 32 + r;
        const int c = cb * 16 + half * 8 + j;
        float v = 0.f;
        if (m < 81) {
          const int k = m / 9, o = m % 9;
          v = w_kernel[(size_t)(o * CC + c) * KTAP + k];
        }
        wkm[i] = f2bf(v);
      }
    }
    return;
  }

  // ---- transpose part (bid 0..9215 = 8n * 72pt * 16ct) ----
  const int n    = bid & 7;           // XCD pin
  const int rest = bid >> 3;
  const int pt = rest % 72;
  const int ct = rest / 72;           // 0..15; 32-ch block
  const int p0 = pt * 32;

  __shared__ float tile[32][33];

  const float* plane = ((ct < 8) ? query : support) +
                       ((size_t)n * CC + (ct & 7) * 32) * HW;
#pragma unroll
  for (int j = 0; j < 4; ++j) {
    const int idx = tid + j * 256;
    const int cc = idx >> 5, pp = idx & 31;
    tile[pp][cc] = plane[(size_t)cc * HW + p0 + pp];
  }
  __syncthreads();

  unsigned short* qn = qsT + (size_t)n * NCG * PPL * 8;
  const int cgbase = ((ct < 8) ? 0 : 32) + (ct & 7) * 4;

  if (tid < 128) {
    const int pp  = tid & 31;
    const int cgl = tid >> 5;          // 0..3
    const int s = p0 + pp;
    const int y = s / 48, x = s % 48;
    const int psite = (y + 2) * 52 + (x + 2);
    const float* row = &tile[pp][cgl * 8];
    uint4 w;
    w.x = (unsigned)f2bf(row[0]) | ((unsigned)f2bf(row[1]) << 16);
    w.y = (unsigned)f2bf(row[2]) | ((unsigned)f2bf(row[3]) << 16);
    w.z = (unsigned)f2bf(row[4]) | ((unsigned)f2bf(row[5]) << 16);
    w.w = (unsigned)f2bf(row[6]) | ((unsigned)f2bf(row[7]) << 16);
    *(uint4*)(qn + ((size_t)(cgbase + cgl) * PPL + psite) * 8) = w;
  }

  // zero border: 400 border sites x 4 cg planes, done by pt==0 blocks
  if (pt == 0) {
    const uint4 zz = make_uint4(0u, 0u, 0u, 0u);
    for (int z = tid; z < 1600; z += 256) {
      const int cgl = z / 400;
      const int e   = z % 400;
      int row, col;
      if (e < 104)      { row = e / 52;              col = e % 52; }          // rows 0,1
      else if (e < 208) { row = 50 + (e - 104) / 52; col = (e - 104) % 52; }  // rows 50,51
      else {
        const int f = e - 208;                                               // cols 0,1,50,51
        row = 2 + f / 4;
        const int cs = f % 4;
        col = (cs < 2) ? cs : (48 + cs);
      }
      *(uint4*)(qn + ((size_t)(cgbase + cgl) * PPL + row * 52 + col) * 8) = zz;
    }
  }
}

// ---------------------------------------------------------------------------
// Kernel 2 (merged): blocks 0..1535 = offset conv (G1=16, 26.6KB LDS,
// asymmetric-depth pipeline, XCD-pinned); blocks 1536..2111 = deform GEMM
// D[n][m][site] (depends only on qsT/wkm, overlaps conv's tail). 192 thr.
// NOTE: no s_setprio — R20 A/B showed it costs ~2us here (lockstep phases).
// ---------------------------------------------------------------------------
__global__ __launch_bounds__(192, 2) void conv_gemm_kernel(
    const unsigned short* __restrict__ qsT,
    const unsigned short* __restrict__ Wm,
    const unsigned short* __restrict__ wkm,
    float* __restrict__ offs_part, float* __restrict__ D) {
  const int bid = blockIdx.x;
  const int tid = threadIdx.x;
  const int w = tid >> 6;
  const int l = tid & 63;
  const int l31 = l & 31;
  const int half = l >> 5;

  __shared__ __align__(16) unsigned short lds[1664 * 8];   // 26,624 B (conv only)

  if (bid >= NCONVB) {
    // ---- deform GEMM part: D[n][m][site] = sum_c wk * sup, m=k*9+o ----
    const int b2 = bid - NCONVB;        // 0..575
    const int n    = b2 & 7;            // XCD pin
    const int rest = b2 >> 3;           // 0..71
    const int wid = rest * 3 + w;       // 0..215
    const int st = wid % 72;            // site tile
    const int mt = wid / 72;            // m tile 0..2
    const int s = st * 32 + l31;
    const int psite = (s / 48) * 52 + (s % 48) + 2 * 52 + 2;

    const unsigned short* qn = qsT + (size_t)n * NCG * PPL * 8;
    const unsigned short* asrc = wkm + (size_t)(half * 32 + l31) * 8;

    f32x16 acc = {0.f, 0.f, 0.f, 0.f, 0.f, 0.f, 0.f, 0.f,
                  0.f, 0.f, 0.f, 0.f, 0.f, 0.f, 0.f, 0.f};

#pragma unroll
    for (int cb = 0; cb < 16; ++cb) {
      const int cg = 32 + cb * 2 + half;
      const short8 b = *(const short8*)(qn + ((size_t)cg * PPL + psite) * 8);
      const short8 a = *(const short8*)(asrc + (size_t)((mt * 16 + cb) * 2) * 256);
      acc = __builtin_amdgcn_mfma_f32_32x32x16_bf16(a, b, acc, 0, 0, 0);
    }

    float* Dn = D + (size_t)n * MM * HW;
#pragma unroll
    for (int r = 0; r < 16; ++r) {
      const int m = mt * 32 + (r & 3) + 8 * (r >> 2) + 4 * half;
      Dn[(size_t)m * HW + s] = acc[r];
    }
    return;
  }

  // ---- offset conv part (bid 0..1535 = 12rt * 16g * 8n) ----
  const int n  = bid & 7;            // XCD pin
  const int r2 = bid >> 3;           // 0..191
  const int g  = r2 & 15;            // channel group (32 ch)
  const int rt = r2 >> 4;            // 0..11 (4 image rows each)

  // ---- stage: cg 0..3 (abs g*4+cg), padded rows rt*4..rt*4+7, cols 0..51 ----
  const unsigned short* qn = qsT + ((size_t)n * NCG + g * 4) * PPL * 8;
  for (int c = tid; c < 1664; c += 192) {
    const int cg  = c / 416;
    const int rem = c - cg * 416;                    // rr*52 + col
    const uint4 v = *(const uint4*)(qn + ((size_t)cg * PPL + rt * 4 * 52 + rem) * 8);
    *(uint4*)(lds + (size_t)c * 8) = v;
  }
  __syncthreads();

  const int si0 = w * 64 + l31;      // first site (0..191 within row tile)
  const int si1 = si0 + 32;          // second site
  const int rrA = si0 / 48, xA = si0 % 48;
  const int rrB = si1 / 48, xB = si1 % 48;

  const unsigned short* lbase0 = lds + (half * 416 + rrA * 52 + xA) * 8;
  const unsigned short* lbase1 = lds + (half * 416 + rrB * 52 + xB) * 8;
  const unsigned short* abase = Wm + (size_t)((g * 4 + half) * 32 + l31) * 8;
  // A(t,kk) = abase + t*16384 + kk*512 (shorts); cb = g*4 + kk*2 + half
  // B(t,kk,site) = lbase + kk*6656 + ((t/5)*52 + t%5)*8 (shorts, compile-time)

  f32x16 acc0 = {0.f, 0.f, 0.f, 0.f, 0.f, 0.f, 0.f, 0.f,
                 0.f, 0.f, 0.f, 0.f, 0.f, 0.f, 0.f, 0.f};
  f32x16 acc1 = acc0;

  short8 a[3][2];                    // [t%3][kk] — A prefetched 2 taps ahead
  short8 b0[2][2], b1[2][2];         // [t&1][kk] — B prefetched 1 tap ahead

  // prologue: A taps 0,1; B tap 0
#pragma unroll
  for (int kk = 0; kk < 2; ++kk) {
    a[0][kk]  = *(const short8*)(abase + 0 * 16384 + kk * 512);
    a[1][kk]  = *(const short8*)(abase + 1 * 16384 + kk * 512);
    b0[0][kk] = *(const short8*)(lbase0 + kk * 6656);
    b1[0][kk] = *(const short8*)(lbase1 + kk * 6656);
  }

#pragma unroll
  for (int t = 0; t < 25; ++t) {
    const int bc = t & 1;            // current B buffer
    const int ac = t % 3;            // current A buffer
    if (t < 24) {
      const int tn = t + 1;
      const int loff = ((tn / 5) * 52 + (tn % 5)) * 8;   // compile-time
#pragma unroll
      for (int kk = 0; kk < 2; ++kk) {
        b0[bc ^ 1][kk] = *(const short8*)(lbase0 + kk * 6656 + loff);
        b1[bc ^ 1][kk] = *(const short8*)(lbase1 + kk * 6656 + loff);
      }
    }
    if (t < 23) {
      const int ta = t + 2;
#pragma unroll
      for (int kk = 0; kk < 2; ++kk)
        a[(t + 2) % 3][kk] = *(const short8*)(abase + ta * 16384 + kk * 512);
    }
    __builtin_amdgcn_sched_barrier(0);
#pragma unroll
    for (int kk = 0; kk < 2; ++kk) {
      acc0 = __builtin_amdgcn_mfma_f32_32x32x16_bf16(a[ac][kk], b0[bc][kk], acc0, 0, 0, 0);
      acc1 = __builtin_amdgcn_mfma_f32_32x32x16_bf16(a[ac][kk], b1[bc][kk], acc1, 0, 0, 0);
    }
  }

  float* dst = offs_part + ((size_t)(g * NN + n) * OCONV) * HW;
  const int s0 = rt * 192 + si0;
  const int s1 = rt * 192 + si1;
#pragma unroll
  for (int r = 0; r < 16; ++r) {
    const int o = (r & 3) + 8 * (r >> 2) + 4 * half;
    if (o < OCONV) {
      dst[(size_t)o * HW + s0] = acc0[r];
      dst[(size_t)o * HW + s1] = acc1[r];
    }
  }
}

// ---------------------------------------------------------------------------
// Kernel 3: fold split-K partials + precompute bilinear params.
// par[n][k][p][8]: {w00,w01,w10,w11 (f32), a00,a01,a10,a11 (int)}. XCD-pinned.
// ---------------------------------------------------------------------------
__global__ __launch_bounds__(256) void param_kernel(
    const float* __restrict__ offs_part, float* __restrict__ par) {
  const int n  = blockIdx.x & 7;       // XCD pin
  const int j  = blockIdx.x >> 3;      // 0..80
  const int il = j * 256 + threadIdx.x;
  const int p = il % HW;
  const int k = il / HW;
  const int y = p / WW, x = p % WW;

  float dy = 0.f, dx = 0.f;
#pragma unroll
  for (int g = 0; g < G1; ++g) {
    const float* base = offs_part + ((size_t)(g * NN + n) * OCONV + 2 * k) * HW + p;
    dy += base[0];
    dx += base[HW];
  }
  const float sy = (float)(y + k / 3 - 1) + dy;
  const float sx = (float)(x + k % 3 - 1) + dx;
  const float y0 = floorf(sy), x0 = floorf(sx);
  const float ly = sy - y0,  lx = sx - x0;
  const float y1 = y0 + 1.f, x1 = x0 + 1.f;
  const float vy0 = (y0 >= 0.f && y0 <= (float)(HH - 1)) ? 1.f : 0.f;
  const float vy1 = (y1 >= 0.f && y1 <= (float)(HH - 1)) ? 1.f : 0.f;
  const float vx0 = (x0 >= 0.f && x0 <= (float)(WW - 1)) ? 1.f : 0.f;
  const float vx1 = (x1 >= 0.f && x1 <= (float)(WW - 1)) ? 1.f : 0.f;
  const int yi0 = min(max((int)y0, 0), HH - 1);
  const int yi1 = min(max((int)y1, 0), HH - 1);
  const int xi0 = min(max((int)x0, 0), WW - 1);
  const int xi1 = min(max((int)x1, 0), WW - 1);

  float* d = par + ((size_t)n * KTAP * HW + il) * 8;
  d[0] = (1.f - ly) * (1.f - lx) * vy0 * vx0;
  d[1] = (1.f - ly) * lx * vy0 * vx1;
  d[2] = ly * (1.f - lx) * vy1 * vx0;
  d[3] = ly * lx * vy1 * vx1;
  int* di = (int*)d;
  di[4] = yi0 * WW + xi0;
  di[5] = yi0 * WW + xi1;
  di[6] = yi1 * WW + xi0;
  di[7] = yi1 * WW + xi1;
}

// ---------------------------------------------------------------------------
// Kernel 4: combine + sigmoid. One thread per output element. XCD-pinned.
// ---------------------------------------------------------------------------
__global__ __launch_bounds__(256) void deform_combine(
    const float* __restrict__ D, const float* __restrict__ par,
    float* __restrict__ out) {
  const int bid = blockIdx.x;          // 648 = 81 * 8n
  const int n  = bid & 7;              // XCD pin
  const int rr = bid >> 3;             // 0..80
  const int o  = rr / 9;
  const int p  = (rr % 9) * 256 + threadIdx.x;

  const float* Dn = D + (size_t)n * MM * HW;
  const float* pb = par + ((size_t)n * KTAP * HW + p) * 8;

  float s = 0.f;
#pragma unroll
  for (int k = 0; k < KTAP; ++k) {
    const float4 wv = *(const float4*)(pb + (size_t)k * HW * 8);
    const int4  av = *(const int4*)(pb + (size_t)k * HW * 8 + 4);
    const float* base = Dn + (size_t)(k * 9 + o) * HW;
    s += wv.x * base[av.x] + wv.y * base[av.y] +
         wv.z * base[av.z] + wv.w * base[av.w];
  }
  out[((size_t)n * KTAP + o) * HW + p] = 1.f / (1.f + __expf(-s));
}

extern "C" void kernel_launch(void* const* d_in, const int* in_sizes, int n_in,
                              void* d_out, int out_size, void* d_ws, size_t ws_size,
                              hipStream_t stream) {
  const float* support  = (const float*)d_in[0];
  const float* query    = (const float*)d_in[1];
  const float* w_off    = (const float*)d_in[2];
  const float* w_kernel = (const float*)d_in[3];
  float* out = (float*)d_out;

  // ws layout (float units), ~46 MB (no aliasing; ws is ~268 MB):
  // [qsT 22.2MB][par 5.3MB][Wm 0.82MB][wkm 0.1MB][offs_part 21.2MB][D 7.1MB]
  float* base = (float*)d_ws;
  unsigned short* qsT = (unsigned short*)base;                  // 8*64*PPL*8 bf16
  float* par = base + (size_t)NN * NCG * PPL * 8 / 2;           // NN*9*HW*8 f
  float* tail = par + (size_t)NN * KTAP * HW * 8;
  unsigned short* Wm  = (unsigned short*)tail;                  // 409600 bf16 = 204800 f
  unsigned short* wkm = (unsigned short*)(tail + 204800);       // 49152 bf16 = 24576 f
  float* offs_part = tail + 204800 + 24576;                     // G1*NSZ f
  float* D = offs_part + (size_t)G1 * NSZ;                      // NN*MM*HW f

  transpose_prep_kernel<<<9216 + 1696, 256, 0, stream>>>(
      support, query, w_off, w_kernel, qsT, Wm, wkm);
  conv_gemm_kernel<<<NCONVB + NGEMMB, 192, 0, stream>>>(qsT, Wm, wkm, offs_part, D);
  param_kernel<<<81 * 8, 256, 0, stream>>>(offs_part, par);
  deform_combine<<<81 * 8, 256, 0, stream>>>(D, par, out);
}